// Round 1
// baseline (84.882 us; speedup 1.0000x reference)
//
#include <hip/hip_runtime.h>

typedef unsigned short u16;
typedef unsigned int   u32;
typedef float f32x4 __attribute__((ext_vector_type(4)));
typedef u16   u16x8 __attribute__((ext_vector_type(8)));
typedef short s16x8 __attribute__((ext_vector_type(8)));

#define B_  8
#define S_  4096
#define D_  2048
#define E_  64
#define M_  (B_ * S_)   // 32768 rows
#define BM  64
#define BK  64
#define LDP 72          // padded LDS row stride in u16 elements (144 B)

__device__ __forceinline__ u16 f2bf(float f) {
  u32 u = __builtin_bit_cast(u32, f);
  u += 0x7fffu + ((u >> 16) & 1u);   // RNE to bf16
  return (u16)(u >> 16);
}
__device__ __forceinline__ float bf2f(u16 h) {
  u32 u = ((u32)h) << 16;
  return __builtin_bit_cast(float, u);
}

// ---------------- pre-pass: W [D][E] fp32 -> W_hi/W_lo transposed [E][D] bf16 ----
__global__ void w_convert_kernel(const float* __restrict__ W,
                                 u16* __restrict__ whiT, u16* __restrict__ wloT) {
  int i = blockIdx.x * 256 + threadIdx.x;   // 0 .. D*E-1
  int k = i >> 6;
  int e = i & 63;
  float w = W[i];
  u16 h = f2bf(w);
  u16 l = f2bf(w - bf2f(h));
  whiT[(size_t)e * D_ + k] = h;
  wloT[(size_t)e * D_ + k] = l;
}

// ---------------- pass 1: logits[t][e] for ALL (b,t) rows via split-bf16 MFMA ----
__launch_bounds__(256)
__global__ void router_gemm_kernel(const float* __restrict__ A,     // [M_][D_]
                                   const u16* __restrict__ WhiT,    // [E_][D_]
                                   const u16* __restrict__ WloT,    // [E_][D_]
                                   float* __restrict__ C) {         // [M_][E_]
  __shared__ __align__(16) u16 Ahi[BM][LDP];
  __shared__ __align__(16) u16 Alo[BM][LDP];
  __shared__ __align__(16) u16 Whi[E_][LDP];
  __shared__ __align__(16) u16 Wlo[E_][LDP];

  const int t    = threadIdx.x;
  const int lane = t & 63;
  const int wid  = t >> 6;
  const int wr   = wid >> 1;           // wave row group (0..1)
  const int wc   = wid & 1;            // wave col group (0..1)
  const int fr   = lane & 15;
  const int fk   = (lane >> 4) * 8;    // k offset within 32-step
  const int row0 = blockIdx.x * BM;

  f32x4 acc[2][2] = {};

  for (int kc = 0; kc < D_; kc += BK) {
    // ---- stage A (fp32 -> hi/lo bf16) and W (pre-converted) into LDS ----
    #pragma unroll
    for (int g = 0; g < 2; ++g) {
      int flat = g * 256 + t;          // 0..511
      int row  = flat >> 3;            // 0..63
      int cb   = flat & 7;             // 16B block within BK row
      const float* src = A + (size_t)(row0 + row) * D_ + kc + cb * 8;
      f32x4 f0 = *(const f32x4*)src;
      f32x4 f1 = *(const f32x4*)(src + 4);
      u16x8 hv, lv;
      #pragma unroll
      for (int j = 0; j < 4; ++j) {
        u16 h = f2bf(f0[j]); hv[j] = h; lv[j] = f2bf(f0[j] - bf2f(h));
      }
      #pragma unroll
      for (int j = 0; j < 4; ++j) {
        u16 h = f2bf(f1[j]); hv[4 + j] = h; lv[4 + j] = f2bf(f1[j] - bf2f(h));
      }
      *(u16x8*)&Ahi[row][cb * 8] = hv;
      *(u16x8*)&Alo[row][cb * 8] = lv;

      // W tile: same flat mapping (e = row index 0..63)
      const u16* wh = WhiT + (size_t)row * D_ + kc + cb * 8;
      const u16* wl = WloT + (size_t)row * D_ + kc + cb * 8;
      *(u16x8*)&Whi[row][cb * 8] = *(const u16x8*)wh;
      *(u16x8*)&Wlo[row][cb * 8] = *(const u16x8*)wl;
    }
    __syncthreads();

    // ---- compute: 2 k-steps of 32, 2x2 16x16 fragments, 3 MFMA passes ----
    #pragma unroll
    for (int ks = 0; ks < 2; ++ks) {
      const int kb = ks * 32 + fk;
      s16x8 ah[2], al[2], wh[2], wl[2];
      #pragma unroll
      for (int m = 0; m < 2; ++m) {
        int r = wr * 32 + m * 16 + fr;
        ah[m] = *(const s16x8*)&Ahi[r][kb];
        al[m] = *(const s16x8*)&Alo[r][kb];
      }
      #pragma unroll
      for (int n = 0; n < 2; ++n) {
        int e = wc * 32 + n * 16 + fr;
        wh[n] = *(const s16x8*)&Whi[e][kb];
        wl[n] = *(const s16x8*)&Wlo[e][kb];
      }
      #pragma unroll
      for (int m = 0; m < 2; ++m)
        #pragma unroll
        for (int n = 0; n < 2; ++n) {
          acc[m][n] = __builtin_amdgcn_mfma_f32_16x16x32_bf16(al[m], wh[n], acc[m][n], 0, 0, 0);
          acc[m][n] = __builtin_amdgcn_mfma_f32_16x16x32_bf16(ah[m], wl[n], acc[m][n], 0, 0, 0);
          acc[m][n] = __builtin_amdgcn_mfma_f32_16x16x32_bf16(ah[m], wh[n], acc[m][n], 0, 0, 0);
        }
    }
    __syncthreads();
  }

  // ---- epilogue: C/D layout col=lane&15, row=(lane>>4)*4+reg (verified mapping) ----
  #pragma unroll
  for (int m = 0; m < 2; ++m)
    #pragma unroll
    for (int n = 0; n < 2; ++n) {
      int ocol = wc * 32 + n * 16 + (lane & 15);
      int orow = row0 + wr * 32 + m * 16 + (lane >> 4) * 4;
      #pragma unroll
      for (int r = 0; r < 4; ++r)
        C[(size_t)(orow + r) * E_ + ocol] = acc[m][n][r];
    }
}

// ---------------- pass 2: gather logits row, top-4, softmax, scatter ----
__launch_bounds__(256)
__global__ void topk_kernel(const float* __restrict__ logits,   // [M_][E_]
                            const int* __restrict__ idxs,       // [M_]
                            float* __restrict__ out) {          // [M_][E_]
  const int lane = threadIdx.x & 63;
  const int wid  = threadIdx.x >> 6;
  const int r    = blockIdx.x * 4 + wid;      // output row
  const int b    = r >> 12;                   // / S_
  const int idx  = idxs[r];

  float cur = logits[((size_t)b * S_ + idx) * E_ + lane];

  float vals[4];
  int   inds[4];
  #pragma unroll
  for (int tk = 0; tk < 4; ++tk) {
    float mv = cur;
    int   mi = lane;
    #pragma unroll
    for (int off = 32; off > 0; off >>= 1) {
      float ov = __shfl_xor(mv, off);
      int   oi = __shfl_xor(mi, off);
      // larger value wins; tie -> smaller index (jax.lax.top_k semantics)
      if (ov > mv || (ov == mv && oi < mi)) { mv = ov; mi = oi; }
    }
    vals[tk] = mv;
    inds[tk] = mi;
    if (lane == mi) cur = -INFINITY;
  }

  float w[4], ssum = 0.f;
  #pragma unroll
  for (int tk = 0; tk < 4; ++tk) { w[tk] = __expf(vals[tk] - vals[0]); ssum += w[tk]; }
  float inv = 1.f / ssum;
  float o = 0.f;
  #pragma unroll
  for (int tk = 0; tk < 4; ++tk)
    if (lane == inds[tk]) o = w[tk] * inv;

  out[(size_t)r * E_ + lane] = o;
}

// ---------------- host ----------------
extern "C" void kernel_launch(void* const* d_in, const int* in_sizes, int n_in,
                              void* d_out, int out_size, void* d_ws, size_t ws_size,
                              hipStream_t stream) {
  const float* hidden = (const float*)d_in[0];   // [8][4096][2048] fp32
  const int*   idxs   = (const int*)d_in[1];     // [8][4096] int32
  const float* W      = (const float*)d_in[2];   // [2048][64] fp32
  float* out = (float*)d_out;                    // [8][4096][64] fp32

  // workspace layout: logits (8 MB) | WhiT (256 KB) | WloT (256 KB)
  float* logits = (float*)d_ws;
  u16* whiT = (u16*)((char*)d_ws + (size_t)M_ * E_ * sizeof(float));
  u16* wloT = whiT + (size_t)E_ * D_;

  w_convert_kernel<<<(D_ * E_) / 256, 256, 0, stream>>>(W, whiT, wloT);
  router_gemm_kernel<<<M_ / BM, 256, 0, stream>>>(hidden, whiT, wloT, logits);
  topk_kernel<<<M_ / 4, 256, 0, stream>>>(logits, idxs, out);
}